// Round 19
// baseline (110.115 us; speedup 1.0000x reference)
//
#include <hip/hip_runtime.h>
#include <hip/hip_bf16.h>
#include <cstdint>

#define T_TOK 1024
#define H_DIM 1024
#define I_DIM 512
#define E_NUM 16
#define TOPK  4

typedef __bf16 bf16;
typedef __bf16 bf16x4 __attribute__((ext_vector_type(4)));
typedef __bf16 bf16x8 __attribute__((ext_vector_type(8)));
typedef float  f32x4  __attribute__((ext_vector_type(4)));
typedef unsigned int u32x2 __attribute__((ext_vector_type(2)));

#define GLOAD16(g, l)                                                                   \
  __builtin_amdgcn_global_load_lds((const __attribute__((address_space(1))) void*)(g),  \
                                   (__attribute__((address_space(3))) void*)(l), 16, 0, 0)

__device__ __forceinline__ unsigned lds_addr(const bf16* p) {
  return (unsigned)(uintptr_t)(const __attribute__((address_space(3))) bf16*)p;
}

// hardware transpose read: lane l receives column (l&15) (4 bf16, rows j=0..3) of the
// 4x16 subtile whose 16 lanes supply base + (l&15)*8 bytes. OFF walks k-subtiles.
template <int OFF>
__device__ __forceinline__ bf16x4 tr_read(unsigned addr) {
  bf16x4 r;
  if constexpr (OFF == 0)
    asm volatile("ds_read_b64_tr_b16 %0, %1" : "=v"(r) : "v"(addr));
  else if constexpr (OFF == 512)
    asm volatile("ds_read_b64_tr_b16 %0, %1 offset:512" : "=v"(r) : "v"(addr));
  else
    asm volatile("ds_read_b64_tr_b16 %0, %1 offset:1024" : "=v"(r) : "v"(addr));
  return r;
}

__device__ __forceinline__ bf16x8 cat8(bf16x4 a, bf16x4 b) {
  return __builtin_shufflevector(a, b, 0, 1, 2, 3, 4, 5, 6, 7);
}

// one convert task: 256 threads x 8 float4-units (8192 floats), 8 loads in flight.
// NONTEMPORAL both directions (native clang vectors): data touched exactly once;
// avoids L2 write/read-allocate churn (the ~2.5 TB/s cap; fillBuffer's nt hits 6.6).
__device__ __forceinline__ void conv_task(const float* __restrict__ src,
                                          bf16* __restrict__ dst, int lt, int tid) {
  const size_t base = (size_t)lt * 2048 + tid;
  const f32x4* s4 = (const f32x4*)src;
  f32x4 f[8];
#pragma unroll
  for (int q = 0; q < 8; ++q) f[q] = __builtin_nontemporal_load(s4 + base + (size_t)q * 256);
  u32x2* d4 = (u32x2*)dst;
#pragma unroll
  for (int q = 0; q < 8; ++q) {
    bf16x4 p;
    p[0] = (bf16)f[q][0]; p[1] = (bf16)f[q][1]; p[2] = (bf16)f[q][2]; p[3] = (bf16)f[q][3];
    u32x2 pv;
    __builtin_memcpy(&pv, &p, 8);
    __builtin_nontemporal_store(pv, d4 + base + (size_t)q * 256);
  }
}

// ================= prep: wgu/sgu/x convert + router_score + init =================
// task space: [0,2048) wgu; [2048,2176) sgu; [2176,2304) x.
// blocks [0,1152) grid-stride 2 tasks; [1152,1408) router_score; [1408,1412) init.
__global__ void prep_kernel(const float* __restrict__ x, bf16* __restrict__ xb,
                            const float* __restrict__ wgu, bf16* __restrict__ wguB,
                            const float* __restrict__ sgu, bf16* __restrict__ sguB,
                            const float* __restrict__ gw,
                            int* __restrict__ topk_e, float* __restrict__ topk_w,
                            int* __restrict__ counts, int* __restrict__ tok,
                            float* __restrict__ wt, int* __restrict__ slot) {
  const int b = blockIdx.x, tid = threadIdx.x;
  if (b < 1152) {
#pragma unroll
    for (int it = 0; it < 2; ++it) {
      const int task = b + it * 1152;
      if (task < 2048)      conv_task(wgu, wguB, task, tid);
      else if (task < 2176) conv_task(sgu, sguB, task - 2048, tid);
      else                  conv_task(x, xb, task - 2176, tid);
    }
  } else if (b < 1408) {     // ---- router_score
    const int wave = tid >> 6, lane = tid & 63;
    const int t = (b - 1152) * 4 + wave;
    const float4* xr = (const float4*)(x + (size_t)t * H_DIM);
    float4 xv[4];
#pragma unroll
    for (int j = 0; j < 4; ++j) xv[j] = xr[lane + 64 * j];
    float p[E_NUM];
#pragma unroll
    for (int e = 0; e < E_NUM; ++e) {
      const float4* gr = (const float4*)(gw + (size_t)e * H_DIM);
      float s = 0.f;
#pragma unroll
      for (int j = 0; j < 4; ++j) {
        float4 g = gr[lane + 64 * j];
        s += xv[j].x * g.x + xv[j].y * g.y + xv[j].z * g.z + xv[j].w * g.w;
      }
      p[e] = s;
    }
#pragma unroll
    for (int off = 32; off > 0; off >>= 1) {
#pragma unroll
      for (int e = 0; e < E_NUM; ++e) p[e] += __shfl_xor(p[e], off);
    }
    float rem[E_NUM];
#pragma unroll
    for (int e = 0; e < E_NUM; ++e) rem[e] = 1.f / (1.f + __expf(-p[e]));
    float vals[TOPK]; int idx[TOPK];
#pragma unroll
    for (int k = 0; k < TOPK; ++k) {
      float m = rem[0]; int mi = 0;
#pragma unroll
      for (int e = 1; e < E_NUM; ++e) {
        if (rem[e] > m) { m = rem[e]; mi = e; }
      }
      vals[k] = m; idx[k] = mi;
#pragma unroll
      for (int e = 0; e < E_NUM; ++e) rem[e] = (e == mi) ? -1e30f : rem[e];
    }
    if (lane == 0) {
      float inv = 1.f / (vals[0] + vals[1] + vals[2] + vals[3]);
      int4 ids; ids.x = idx[0]; ids.y = idx[1]; ids.z = idx[2]; ids.w = idx[3];
      float4 w4; w4.x = vals[0]*inv; w4.y = vals[1]*inv; w4.z = vals[2]*inv; w4.w = vals[3]*inv;
      ((int4*)topk_e)[t] = ids;
      ((float4*)topk_w)[t] = w4;
    }
  } else {                   // ---- init shared-expert list
    const int i = (b - 1408) * 256 + tid;
    if (i == 0) counts[E_NUM] = T_TOK;
    tok [E_NUM * T_TOK + i] = i;
    wt  [E_NUM * T_TOK + i] = 1.0f;
    slot[E_NUM * T_TOK + i] = T_TOK * TOPK + i;
  }
}

// ---------------- router phase 2: per-expert list build via ballot prefix ----------------
__global__ void router_build_kernel(const int* __restrict__ topk_e, const float* __restrict__ topk_w,
                                    int* __restrict__ counts, int* __restrict__ tok,
                                    float* __restrict__ wt, int* __restrict__ slot) {
  const int e = blockIdx.x;
  const int tid = threadIdx.x, wave = tid >> 6, lane = tid & 63;
  __shared__ int wsum[4];
  int base = 0;
  for (int r = 0; r < 4; ++r) {
    int t = r * 256 + tid;
    int4 ids = ((const int4*)topk_e)[t];
    int match = -1;
    if (ids.x == e) match = 0;
    if (ids.y == e) match = 1;
    if (ids.z == e) match = 2;
    if (ids.w == e) match = 3;
    unsigned long long bm = __ballot(match >= 0);
    int prefix = __popcll(bm & ((1ull << lane) - 1ull));
    if (lane == 0) wsum[wave] = __popcll(bm);
    __syncthreads();
    int wbase = 0;
#pragma unroll
    for (int wv = 0; wv < 4; ++wv) wbase += (wv < wave) ? wsum[wv] : 0;
    int total = wsum[0] + wsum[1] + wsum[2] + wsum[3];
    if (match >= 0) {
      int pos = base + wbase + prefix;
      tok [e * T_TOK + pos] = t;
      wt  [e * T_TOK + pos] = topk_w[t * 4 + match];
      slot[e * T_TOK + pos] = t * 4 + match;
    }
    base += total;
    __syncthreads();
  }
  if (tid == 0) counts[e] = base;
}

// ---------------- GEMM1 (z<17) + wd/sd convert blocks (z>=17) ----------------
__global__ __launch_bounds__(256, 4)
void gemm1_kernel(const bf16* __restrict__ xb, const bf16* __restrict__ wguB,
                  const bf16* __restrict__ sguB, const int* __restrict__ counts,
                  const int* __restrict__ tok, const float* __restrict__ wt,
                  const int* __restrict__ slot, bf16* __restrict__ hbuf,
                  const float* __restrict__ wdF, bf16* __restrict__ wdBo,
                  const float* __restrict__ sdF, bf16* __restrict__ sdBo) {
  const int tid = threadIdx.x;
  const int e = blockIdx.z;
  if (e >= 17) {  // ---- convert role: wd (1024 tasks) + sd (64 tasks)
    const int cid = (e - 17) * 128 + blockIdx.y * 8 + blockIdx.x;
    if (cid < 1024)      conv_task(wdF, wdBo, cid, tid);
    else if (cid < 1088) conv_task(sdF, sdBo, cid - 1024, tid);
    return;
  }
  const int cnt = counts[e];
  const int rt  = blockIdx.y;
  if (rt * 64 >= cnt) return;
  const int nb = blockIdx.x * 64;
  const bf16* WB = (e < E_NUM) ? (wguB + (size_t)e * H_DIM * (2 * I_DIM)) : sguB;

  __shared__ __align__(16) bf16 sA[3][64 * 32];
  __shared__ __align__(16) bf16 sG[3][2048];
  __shared__ __align__(16) bf16 sU[3][2048];

  const int wave = tid >> 6, lane = tid & 63;
  const int wr = wave >> 1, wc = wave & 1;
  const int fr = lane & 15, kg = lane >> 4;
  const int lr = lane >> 2, lk = (lane & 3) * 8;

  int ar = rt * 64 + wave * 16 + lr;
  int arc = ar < cnt ? ar : cnt - 1;
  const bf16* aS = xb + (size_t)tok[e * T_TOK + arc] * H_DIM + lk;
  const int aOff = wave * 512;

  const int k_off = 8 * wave + 4 * (lane >> 5) + ((lane & 7) >> 1);
  const int n_off = 16 * ((lane >> 3) & 3) + 8 * (lane & 1);
  const bf16* gS = WB + (size_t)k_off * (2 * I_DIM) + nb + n_off;
  const bf16* uS = WB + (size_t)k_off * (2 * I_DIM) + I_DIM + nb + n_off;
  const int wOff = wave * 512;

  f32x4 accg[2][2], accu[2][2];
#pragma unroll
  for (int i = 0; i < 2; ++i)
#pragma unroll
    for (int j = 0; j < 2; ++j) { accg[i][j] = f32x4{0,0,0,0}; accu[i][j] = f32x4{0,0,0,0}; }

#define STG1(t, bidx) do { size_t ko = (size_t)(t) * 32;    \
    GLOAD16(aS + ko, sA[bidx] + aOff);                      \
    GLOAD16(gS + ko * (2 * I_DIM), sG[bidx] + wOff);        \
    GLOAD16(uS + ko * (2 * I_DIM), sU[bidx] + wOff); } while (0)

  STG1(0, 0); STG1(1, 1);
  const int NT = H_DIM / 32;  // 32
  int bufc = 0;
  for (int t = 0; t < NT; ++t) {
    int bn = bufc + 2; bn = bn >= 3 ? bn - 3 : bn;
    if (t + 2 < NT) {
      STG1(t + 2, bn);
      asm volatile("s_waitcnt vmcnt(6)" ::: "memory");
    } else if (t + 1 < NT) {
      asm volatile("s_waitcnt vmcnt(3)" ::: "memory");
    } else {
      asm volatile("s_waitcnt vmcnt(0)" ::: "memory");
    }
    __builtin_amdgcn_s_barrier();
    __builtin_amdgcn_sched_barrier(0);
    const bf16* A = sA[bufc];
    bf16x8 a0 = *(const bf16x8*)(A + (wr * 32      + fr) * 32 + kg * 8);
    bf16x8 a1 = *(const bf16x8*)(A + (wr * 32 + 16 + fr) * 32 + kg * 8);
    unsigned gb = lds_addr(sG[bufc]) + (unsigned)((lane >> 4) << 10) + (unsigned)((lane & 15) << 3);
    unsigned ub = lds_addr(sU[bufc]) + (unsigned)((lane >> 4) << 10) + (unsigned)((lane & 15) << 3);
    unsigned nb0 = (unsigned)(wc * 256), nb1 = nb0 + 128;
    bf16x8 g0 = cat8(tr_read<0>(gb + nb0), tr_read<512>(gb + nb0));
    bf16x8 g1 = cat8(tr_read<0>(gb + nb1), tr_read<512>(gb + nb1));
    bf16x8 u0 = cat8(tr_read<0>(ub + nb0), tr_read<512>(ub + nb0));
    bf16x8 u1 = cat8(tr_read<0>(ub + nb1), tr_read<512>(ub + nb1));
    asm volatile("s_waitcnt lgkmcnt(0)" ::: "memory");
    __builtin_amdgcn_sched_barrier(0);
    __builtin_amdgcn_s_setprio(1);
    accg[0][0] = __builtin_amdgcn_mfma_f32_16x16x32_bf16(a0, g0, accg[0][0], 0, 0, 0);
    accg[0][1] = __builtin_amdgcn_mfma_f32_16x16x32_bf16(a0, g1, accg[0][1], 0, 0, 0);
    accg[1][0] = __builtin_amdgcn_mfma_f32_16x16x32_bf16(a1, g0, accg[1][0], 0, 0, 0);
    accg[1][1] = __builtin_amdgcn_mfma_f32_16x16x32_bf16(a1, g1, accg[1][1], 0, 0, 0);
    accu[0][0] = __builtin_amdgcn_mfma_f32_16x16x32_bf16(a0, u0, accu[0][0], 0, 0, 0);
    accu[0][1] = __builtin_amdgcn_mfma_f32_16x16x32_bf16(a0, u1, accu[0][1], 0, 0, 0);
    accu[1][0] = __builtin_amdgcn_mfma_f32_16x16x32_bf16(a1, u0, accu[1][0], 0, 0, 0);
    accu[1][1] = __builtin_amdgcn_mfma_f32_16x16x32_bf16(a1, u1, accu[1][1], 0, 0, 0);
    __builtin_amdgcn_s_setprio(0);
    __builtin_amdgcn_sched_barrier(0);
    __builtin_amdgcn_s_barrier();
    bufc = bufc == 2 ? 0 : bufc + 1;
  }
#undef STG1

#pragma unroll
  for (int mi = 0; mi < 2; ++mi) {
#pragma unroll
    for (int j = 0; j < 4; ++j) {
      int grow = rt * 64 + wr * 32 + mi * 16 + kg * 4 + j;
      if (grow < cnt) {
        bf16* hr = hbuf + (size_t)slot[e * T_TOK + grow] * I_DIM;
        float w = wt[e * T_TOK + grow];
#pragma unroll
        for (int ni = 0; ni < 2; ++ni) {
          float g = accg[mi][ni][j], u = accu[mi][ni][j];
          float h = w * (g / (1.f + __expf(-g))) * u;
          hr[nb + wc * 32 + ni * 16 + fr] = (bf16)h;
        }
      }
    }
  }
}

// ---------------- GEMM2: h gathered @ Wd(natural bf16) -> bf16 stores into obuf ----------------
__global__ __launch_bounds__(256, 4)
void gemm2_kernel(const bf16* __restrict__ hbuf, const bf16* __restrict__ wdB,
                  const bf16* __restrict__ sdB, const int* __restrict__ counts,
                  const int* __restrict__ slot, bf16* __restrict__ obuf) {
  const int e   = blockIdx.z;
  const int cnt = counts[e];
  const int rt  = blockIdx.y;
  if (rt * 64 >= cnt) return;
  const int nb = blockIdx.x * 128;
  const bf16* WB = (e < E_NUM) ? (wdB + (size_t)e * I_DIM * H_DIM) : sdB;

  __shared__ __align__(16) bf16 sA[3][64 * 32];
  __shared__ __align__(16) bf16 sB[3][4096];

  const int tid = threadIdx.x, wave = tid >> 6, lane = tid & 63;
  const int wr = wave >> 1, wc = wave & 1;
  const int fr = lane & 15, kg = lane >> 4;
  const int lr = lane >> 2, lk = (lane & 3) * 8;

  int ar = rt * 64 + wave * 16 + lr;
  int arc = ar < cnt ? ar : cnt - 1;
  const bf16* aS = hbuf + (size_t)slot[e * T_TOK + arc] * I_DIM + lk;
  const int aOff = wave * 512;

  const int j2 = (lane & 7) >> 1, h2 = lane & 1, nblk2 = lane >> 3;
  const int n2 = nb + nblk2 * 16 + 8 * h2;
  const bf16* bS0 = WB + (size_t)((wave * 2 + 0) * 4 + j2) * H_DIM + n2;
  const bf16* bS1 = WB + (size_t)((wave * 2 + 1) * 4 + j2) * H_DIM + n2;
  const int bOff0 = wave * 1024;
  const int bOff1 = bOff0 + 512;

  f32x4 acc[2][4];
#pragma unroll
  for (int i = 0; i < 2; ++i)
#pragma unroll
    for (int j = 0; j < 4; ++j) acc[i][j] = f32x4{0,0,0,0};

#define STG2(t, bidx) do { size_t ko = (size_t)(t) * 32;    \
    GLOAD16(aS + ko, sA[bidx] + aOff);                      \
    GLOAD16(bS0 + ko * H_DIM, sB[bidx] + bOff0);            \
    GLOAD16(bS1 + ko * H_DIM, sB[bidx] + bOff1); } while (0)

  STG2(0, 0); STG2(1, 1);
  const int NT = I_DIM / 32;  // 16
  int bufc = 0;
  for (int t = 0; t < NT; ++t) {
    int bn = bufc + 2; bn = bn >= 3 ? bn - 3 : bn;
    if (t + 2 < NT) {
      STG2(t + 2, bn);
      asm volatile("s_waitcnt vmcnt(6)" ::: "memory");
    } else if (t + 1 < NT) {
      asm volatile("s_waitcnt vmcnt(3)" ::: "memory");
    } else {
      asm volatile("s_waitcnt vmcnt(0)" ::: "memory");
    }
    __builtin_amdgcn_s_barrier();
    __builtin_amdgcn_sched_barrier(0);
    const bf16* A = sA[bufc];
    bf16x8 a0 = *(const bf16x8*)(A + (wr * 32      + fr) * 32 + kg * 8);
    bf16x8 a1 = *(const bf16x8*)(A + (wr * 32 + 16 + fr) * 32 + kg * 8);
    unsigned bb = lds_addr(sB[bufc]) + (unsigned)((lane >> 4) << 11) + (unsigned)((lane & 15) << 3)
                + (unsigned)(wc * 512);
    bf16x8 b[4];
#pragma unroll
    for (int ni = 0; ni < 4; ++ni)
      b[ni] = cat8(tr_read<0>(bb + ni * 128), tr_read<1024>(bb + ni * 128));
    asm volatile("s_waitcnt lgkmcnt(0)" ::: "memory");
    __builtin_amdgcn_sched_barrier(0);
    __builtin_amdgcn_s_setprio(1);
#pragma unroll
    for (int ni = 0; ni < 4; ++ni) {
      acc[0][ni] = __builtin_amdgcn_mfma_f32_16x16x32_bf16(a0, b[ni], acc[0][ni], 0, 0, 0);
      acc[1][ni] = __builtin_amdgcn_mfma_f32_16x16x32_bf16(a1, b[ni], acc[1][ni], 0, 0, 0);
    }
    __builtin_amdgcn_s_setprio(0);
    __builtin_amdgcn_sched_barrier(0);
    __builtin_amdgcn_s_barrier();
    bufc = bufc == 2 ? 0 : bufc + 1;
  }
#undef STG2

#pragma unroll
  for (int mi = 0; mi < 2; ++mi) {
#pragma unroll
    for (int j = 0; j < 4; ++j) {
      int grow = rt * 64 + wr * 32 + mi * 16 + kg * 4 + j;
      if (grow < cnt) {
        bf16* orow = obuf + (size_t)slot[e * T_TOK + grow] * H_DIM + nb + wc * 64 + fr;
#pragma unroll
        for (int ni = 0; ni < 4; ++ni)
          orow[ni * 16] = (bf16)acc[mi][ni][j];
      }
    }
  }
}

// ---------------- reduce: out[t] = sum_k obuf[t*4+k] + obuf[4096+t] (bf16 -> fp32) ----------------
__global__ void reduce_kernel(const bf16* __restrict__ obuf, float* __restrict__ out) {
  const int t = blockIdx.x;
  const int c = threadIdx.x;   // 256 chunks of 4 elems per row
  const bf16x4* o4 = (const bf16x4*)obuf;
  float4 s; s.x = s.y = s.z = s.w = 0.f;
  int rows[5] = {t * 4, t * 4 + 1, t * 4 + 2, t * 4 + 3, T_TOK * TOPK + t};
#pragma unroll
  for (int r = 0; r < 5; ++r) {
    bf16x4 v = o4[(size_t)rows[r] * 256 + c];
    s.x += (float)v[0]; s.y += (float)v[1]; s.z += (float)v[2]; s.w += (float)v[3];
  }
  ((float4*)out)[(size_t)t * 256 + c] = s;
}

extern "C" void kernel_launch(void* const* d_in, const int* in_sizes, int n_in,
                              void* d_out, int out_size, void* d_ws, size_t ws_size,
                              hipStream_t stream) {
  const float* x   = (const float*)d_in[0];
  const float* gw  = (const float*)d_in[1];
  const float* wgu = (const float*)d_in[2];
  const float* wd  = (const float*)d_in[3];
  const float* sgu = (const float*)d_in[4];
  const float* sd  = (const float*)d_in[5];
  float* out = (float*)d_out;

  char* ws = (char*)d_ws;
  int*   counts = (int*)  (ws);                 // 1 KB
  int*   tok    = (int*)  (ws + 1024);          // 68 KB
  float* wtA    = (float*)(ws + 70656);         // 68 KB
  int*   slotA  = (int*)  (ws + 140288);        // 68 KB
  int*   topk_e = (int*)  (ws + 209920);        // 16 KB
  float* topk_w = (float*)(ws + 226304);        // 16 KB
  bf16*  xb     = (bf16*) (ws + 245760);        // 2 MB
  bf16*  hbuf   = (bf16*) (ws + 2342912);       // 5.25 MB
  bf16*  wguB   = (bf16*) (ws + 7585792);       // 32 MB  natural [E][1024][1024]
  bf16*  wdB    = (bf16*) (ws + 41140224);      // 16 MB  natural [E][512][1024]
  bf16*  sguB   = (bf16*) (ws + 57917440);      // 2 MB
  bf16*  sdB    = (bf16*) (ws + 60014592);      // 1 MB
  // obuf (10 MB bf16 [5120][1024]) aliases wguB: dead after gemm1, rewritten by
  // prep before gemm1 on every call.
  bf16*  obuf   = (bf16*) (ws + 7585792);

  prep_kernel<<<1412, 256, 0, stream>>>(x, xb, wgu, wguB, sgu, sguB,
                                        gw, topk_e, topk_w, counts, tok, wtA, slotA);
  router_build_kernel<<<E_NUM, 256, 0, stream>>>(topk_e, topk_w, counts, tok, wtA, slotA);
  gemm1_kernel<<<dim3(8, 16, 26), 256, 0, stream>>>(xb, wguB, sguB, counts, tok, wtA, slotA,
                                                    hbuf, wd, wdB, sd, sdB);
  gemm2_kernel<<<dim3(8, 16, 17), 256, 0, stream>>>(hbuf, wdB, sdB, counts, slotA, obuf);
  reduce_kernel<<<T_TOK, 256, 0, stream>>>(obuf, out);
}

// Round 20
// 85.082 us; speedup vs baseline: 1.2942x; 1.2942x over previous
//
#include <hip/hip_runtime.h>
#include <hip/hip_bf16.h>
#include <cstdint>

#define T_TOK 1024
#define H_DIM 1024
#define I_DIM 512
#define E_NUM 16
#define TOPK  4

typedef __bf16 bf16;
typedef __bf16 bf16x4 __attribute__((ext_vector_type(4)));
typedef __bf16 bf16x8 __attribute__((ext_vector_type(8)));
typedef float  f32x4  __attribute__((ext_vector_type(4)));

#define GLOAD16(g, l)                                                                   \
  __builtin_amdgcn_global_load_lds((const __attribute__((address_space(1))) void*)(g),  \
                                   (__attribute__((address_space(3))) void*)(l), 16, 0, 0)

__device__ __forceinline__ unsigned lds_addr(const bf16* p) {
  return (unsigned)(uintptr_t)(const __attribute__((address_space(3))) bf16*)p;
}

// hardware transpose read: lane l receives column (l&15) (4 bf16, rows j=0..3) of the
// 4x16 subtile whose 16 lanes supply base + (l&15)*8 bytes. OFF walks k-subtiles.
template <int OFF>
__device__ __forceinline__ bf16x4 tr_read(unsigned addr) {
  bf16x4 r;
  if constexpr (OFF == 0)
    asm volatile("ds_read_b64_tr_b16 %0, %1" : "=v"(r) : "v"(addr));
  else if constexpr (OFF == 512)
    asm volatile("ds_read_b64_tr_b16 %0, %1 offset:512" : "=v"(r) : "v"(addr));
  else
    asm volatile("ds_read_b64_tr_b16 %0, %1 offset:1024" : "=v"(r) : "v"(addr));
  return r;
}

__device__ __forceinline__ bf16x8 cat8(bf16x4 a, bf16x4 b) {
  return __builtin_shufflevector(a, b, 0, 1, 2, 3, 4, 5, 6, 7);
}

// one convert task: 256 threads x 8 float4-units (8192 floats). Thread owns 4 PAIRS of
// adjacent float4-units -> 8 loads in flight, 4x bf16x8 (16B/lane) stores (m146 width).
__device__ __forceinline__ void conv_task(const float* __restrict__ src,
                                          bf16* __restrict__ dst, int lt, int tid) {
  const size_t b4 = (size_t)lt * 2048 + 2 * tid;
  const float4* s4 = (const float4*)src;
  float4 fa[4], fb[4];
#pragma unroll
  for (int p = 0; p < 4; ++p) {
    fa[p] = s4[b4 + (size_t)p * 512];
    fb[p] = s4[b4 + (size_t)p * 512 + 1];
  }
  bf16x8* d8 = (bf16x8*)dst;
#pragma unroll
  for (int p = 0; p < 4; ++p) {
    bf16x8 o;
    o[0]=(bf16)fa[p].x; o[1]=(bf16)fa[p].y; o[2]=(bf16)fa[p].z; o[3]=(bf16)fa[p].w;
    o[4]=(bf16)fb[p].x; o[5]=(bf16)fb[p].y; o[6]=(bf16)fb[p].z; o[7]=(bf16)fb[p].w;
    d8[(size_t)lt * 1024 + tid + (size_t)p * 256] = o;
  }
}

// ================= prep: wgu/sgu/x convert + router_score + init =================
// task space: [0,2048) wgu; [2048,2176) sgu; [2176,2304) x.
// blocks [0,1152) grid-stride 2 tasks; [1152,1408) router_score; [1408,1412) init.
__global__ void prep_kernel(const float* __restrict__ x, bf16* __restrict__ xb,
                            const float* __restrict__ wgu, bf16* __restrict__ wguB,
                            const float* __restrict__ sgu, bf16* __restrict__ sguB,
                            const float* __restrict__ gw,
                            int* __restrict__ topk_e, float* __restrict__ topk_w,
                            int* __restrict__ counts, int* __restrict__ tok,
                            float* __restrict__ wt, int* __restrict__ slot) {
  const int b = blockIdx.x, tid = threadIdx.x;
  if (b < 1152) {
#pragma unroll
    for (int it = 0; it < 2; ++it) {
      const int task = b + it * 1152;
      if (task < 2048)      conv_task(wgu, wguB, task, tid);
      else if (task < 2176) conv_task(sgu, sguB, task - 2048, tid);
      else                  conv_task(x, xb, task - 2176, tid);
    }
  } else if (b < 1408) {     // ---- router_score
    const int wave = tid >> 6, lane = tid & 63;
    const int t = (b - 1152) * 4 + wave;
    const float4* xr = (const float4*)(x + (size_t)t * H_DIM);
    float4 xv[4];
#pragma unroll
    for (int j = 0; j < 4; ++j) xv[j] = xr[lane + 64 * j];
    float p[E_NUM];
#pragma unroll
    for (int e = 0; e < E_NUM; ++e) {
      const float4* gr = (const float4*)(gw + (size_t)e * H_DIM);
      float s = 0.f;
#pragma unroll
      for (int j = 0; j < 4; ++j) {
        float4 g = gr[lane + 64 * j];
        s += xv[j].x * g.x + xv[j].y * g.y + xv[j].z * g.z + xv[j].w * g.w;
      }
      p[e] = s;
    }
#pragma unroll
    for (int off = 32; off > 0; off >>= 1) {
#pragma unroll
      for (int e = 0; e < E_NUM; ++e) p[e] += __shfl_xor(p[e], off);
    }
    float rem[E_NUM];
#pragma unroll
    for (int e = 0; e < E_NUM; ++e) rem[e] = 1.f / (1.f + __expf(-p[e]));
    float vals[TOPK]; int idx[TOPK];
#pragma unroll
    for (int k = 0; k < TOPK; ++k) {
      float m = rem[0]; int mi = 0;
#pragma unroll
      for (int e = 1; e < E_NUM; ++e) {
        if (rem[e] > m) { m = rem[e]; mi = e; }
      }
      vals[k] = m; idx[k] = mi;
#pragma unroll
      for (int e = 0; e < E_NUM; ++e) rem[e] = (e == mi) ? -1e30f : rem[e];
    }
    if (lane == 0) {
      float inv = 1.f / (vals[0] + vals[1] + vals[2] + vals[3]);
      int4 ids; ids.x = idx[0]; ids.y = idx[1]; ids.z = idx[2]; ids.w = idx[3];
      float4 w4; w4.x = vals[0]*inv; w4.y = vals[1]*inv; w4.z = vals[2]*inv; w4.w = vals[3]*inv;
      ((int4*)topk_e)[t] = ids;
      ((float4*)topk_w)[t] = w4;
    }
  } else {                   // ---- init shared-expert list
    const int i = (b - 1408) * 256 + tid;
    if (i == 0) counts[E_NUM] = T_TOK;
    tok [E_NUM * T_TOK + i] = i;
    wt  [E_NUM * T_TOK + i] = 1.0f;
    slot[E_NUM * T_TOK + i] = T_TOK * TOPK + i;
  }
}

// ---------------- router phase 2: per-expert list build via ballot prefix ----------------
__global__ void router_build_kernel(const int* __restrict__ topk_e, const float* __restrict__ topk_w,
                                    int* __restrict__ counts, int* __restrict__ tok,
                                    float* __restrict__ wt, int* __restrict__ slot) {
  const int e = blockIdx.x;
  const int tid = threadIdx.x, wave = tid >> 6, lane = tid & 63;
  __shared__ int wsum[4];
  int base = 0;
  for (int r = 0; r < 4; ++r) {
    int t = r * 256 + tid;
    int4 ids = ((const int4*)topk_e)[t];
    int match = -1;
    if (ids.x == e) match = 0;
    if (ids.y == e) match = 1;
    if (ids.z == e) match = 2;
    if (ids.w == e) match = 3;
    unsigned long long bm = __ballot(match >= 0);
    int prefix = __popcll(bm & ((1ull << lane) - 1ull));
    if (lane == 0) wsum[wave] = __popcll(bm);
    __syncthreads();
    int wbase = 0;
#pragma unroll
    for (int wv = 0; wv < 4; ++wv) wbase += (wv < wave) ? wsum[wv] : 0;
    int total = wsum[0] + wsum[1] + wsum[2] + wsum[3];
    if (match >= 0) {
      int pos = base + wbase + prefix;
      tok [e * T_TOK + pos] = t;
      wt  [e * T_TOK + pos] = topk_w[t * 4 + match];
      slot[e * T_TOK + pos] = t * 4 + match;
    }
    base += total;
    __syncthreads();
  }
  if (tid == 0) counts[e] = base;
}

// ---------------- GEMM1 (z<17) + wd/sd convert blocks (z>=17) ----------------
__global__ __launch_bounds__(256, 4)
void gemm1_kernel(const bf16* __restrict__ xb, const bf16* __restrict__ wguB,
                  const bf16* __restrict__ sguB, const int* __restrict__ counts,
                  const int* __restrict__ tok, const float* __restrict__ wt,
                  const int* __restrict__ slot, bf16* __restrict__ hbuf,
                  const float* __restrict__ wdF, bf16* __restrict__ wdBo,
                  const float* __restrict__ sdF, bf16* __restrict__ sdBo) {
  const int tid = threadIdx.x;
  const int e = blockIdx.z;
  if (e >= 17) {  // ---- convert role: wd (1024 tasks) + sd (64 tasks)
    const int cid = (e - 17) * 128 + blockIdx.y * 8 + blockIdx.x;
    if (cid < 1024)      conv_task(wdF, wdBo, cid, tid);
    else if (cid < 1088) conv_task(sdF, sdBo, cid - 1024, tid);
    return;
  }
  const int cnt = counts[e];
  const int rt  = blockIdx.y;
  if (rt * 64 >= cnt) return;
  const int nb = blockIdx.x * 64;
  const bf16* WB = (e < E_NUM) ? (wguB + (size_t)e * H_DIM * (2 * I_DIM)) : sguB;

  __shared__ __align__(16) bf16 sA[3][64 * 32];
  __shared__ __align__(16) bf16 sG[3][2048];
  __shared__ __align__(16) bf16 sU[3][2048];

  const int wave = tid >> 6, lane = tid & 63;
  const int wr = wave >> 1, wc = wave & 1;
  const int fr = lane & 15, kg = lane >> 4;
  const int lr = lane >> 2, lk = (lane & 3) * 8;

  int ar = rt * 64 + wave * 16 + lr;
  int arc = ar < cnt ? ar : cnt - 1;
  const bf16* aS = xb + (size_t)tok[e * T_TOK + arc] * H_DIM + lk;
  const int aOff = wave * 512;

  const int k_off = 8 * wave + 4 * (lane >> 5) + ((lane & 7) >> 1);
  const int n_off = 16 * ((lane >> 3) & 3) + 8 * (lane & 1);
  const bf16* gS = WB + (size_t)k_off * (2 * I_DIM) + nb + n_off;
  const bf16* uS = WB + (size_t)k_off * (2 * I_DIM) + I_DIM + nb + n_off;
  const int wOff = wave * 512;

  f32x4 accg[2][2], accu[2][2];
#pragma unroll
  for (int i = 0; i < 2; ++i)
#pragma unroll
    for (int j = 0; j < 2; ++j) { accg[i][j] = f32x4{0,0,0,0}; accu[i][j] = f32x4{0,0,0,0}; }

#define STG1(t, bidx) do { size_t ko = (size_t)(t) * 32;    \
    GLOAD16(aS + ko, sA[bidx] + aOff);                      \
    GLOAD16(gS + ko * (2 * I_DIM), sG[bidx] + wOff);        \
    GLOAD16(uS + ko * (2 * I_DIM), sU[bidx] + wOff); } while (0)

  STG1(0, 0); STG1(1, 1);
  const int NT = H_DIM / 32;  // 32
  int bufc = 0;
  for (int t = 0; t < NT; ++t) {
    int bn = bufc + 2; bn = bn >= 3 ? bn - 3 : bn;
    if (t + 2 < NT) {
      STG1(t + 2, bn);
      asm volatile("s_waitcnt vmcnt(6)" ::: "memory");
    } else if (t + 1 < NT) {
      asm volatile("s_waitcnt vmcnt(3)" ::: "memory");
    } else {
      asm volatile("s_waitcnt vmcnt(0)" ::: "memory");
    }
    __builtin_amdgcn_s_barrier();
    __builtin_amdgcn_sched_barrier(0);
    const bf16* A = sA[bufc];
    bf16x8 a0 = *(const bf16x8*)(A + (wr * 32      + fr) * 32 + kg * 8);
    bf16x8 a1 = *(const bf16x8*)(A + (wr * 32 + 16 + fr) * 32 + kg * 8);
    unsigned gb = lds_addr(sG[bufc]) + (unsigned)((lane >> 4) << 10) + (unsigned)((lane & 15) << 3);
    unsigned ub = lds_addr(sU[bufc]) + (unsigned)((lane >> 4) << 10) + (unsigned)((lane & 15) << 3);
    unsigned nb0 = (unsigned)(wc * 256), nb1 = nb0 + 128;
    bf16x8 g0 = cat8(tr_read<0>(gb + nb0), tr_read<512>(gb + nb0));
    bf16x8 g1 = cat8(tr_read<0>(gb + nb1), tr_read<512>(gb + nb1));
    bf16x8 u0 = cat8(tr_read<0>(ub + nb0), tr_read<512>(ub + nb0));
    bf16x8 u1 = cat8(tr_read<0>(ub + nb1), tr_read<512>(ub + nb1));
    asm volatile("s_waitcnt lgkmcnt(0)" ::: "memory");
    __builtin_amdgcn_sched_barrier(0);
    __builtin_amdgcn_s_setprio(1);
    accg[0][0] = __builtin_amdgcn_mfma_f32_16x16x32_bf16(a0, g0, accg[0][0], 0, 0, 0);
    accg[0][1] = __builtin_amdgcn_mfma_f32_16x16x32_bf16(a0, g1, accg[0][1], 0, 0, 0);
    accg[1][0] = __builtin_amdgcn_mfma_f32_16x16x32_bf16(a1, g0, accg[1][0], 0, 0, 0);
    accg[1][1] = __builtin_amdgcn_mfma_f32_16x16x32_bf16(a1, g1, accg[1][1], 0, 0, 0);
    accu[0][0] = __builtin_amdgcn_mfma_f32_16x16x32_bf16(a0, u0, accu[0][0], 0, 0, 0);
    accu[0][1] = __builtin_amdgcn_mfma_f32_16x16x32_bf16(a0, u1, accu[0][1], 0, 0, 0);
    accu[1][0] = __builtin_amdgcn_mfma_f32_16x16x32_bf16(a1, u0, accu[1][0], 0, 0, 0);
    accu[1][1] = __builtin_amdgcn_mfma_f32_16x16x32_bf16(a1, u1, accu[1][1], 0, 0, 0);
    __builtin_amdgcn_s_setprio(0);
    __builtin_amdgcn_sched_barrier(0);
    __builtin_amdgcn_s_barrier();
    bufc = bufc == 2 ? 0 : bufc + 1;
  }
#undef STG1

#pragma unroll
  for (int mi = 0; mi < 2; ++mi) {
#pragma unroll
    for (int j = 0; j < 4; ++j) {
      int grow = rt * 64 + wr * 32 + mi * 16 + kg * 4 + j;
      if (grow < cnt) {
        bf16* hr = hbuf + (size_t)slot[e * T_TOK + grow] * I_DIM;
        float w = wt[e * T_TOK + grow];
#pragma unroll
        for (int ni = 0; ni < 2; ++ni) {
          float g = accg[mi][ni][j], u = accu[mi][ni][j];
          float h = w * (g / (1.f + __expf(-g))) * u;
          hr[nb + wc * 32 + ni * 16 + fr] = (bf16)h;
        }
      }
    }
  }
}

// ---------------- GEMM2: h gathered @ Wd(natural bf16) -> bf16 stores into obuf ----------------
__global__ __launch_bounds__(256, 4)
void gemm2_kernel(const bf16* __restrict__ hbuf, const bf16* __restrict__ wdB,
                  const bf16* __restrict__ sdB, const int* __restrict__ counts,
                  const int* __restrict__ slot, bf16* __restrict__ obuf) {
  const int e   = blockIdx.z;
  const int cnt = counts[e];
  const int rt  = blockIdx.y;
  if (rt * 64 >= cnt) return;
  const int nb = blockIdx.x * 128;
  const bf16* WB = (e < E_NUM) ? (wdB + (size_t)e * I_DIM * H_DIM) : sdB;

  __shared__ __align__(16) bf16 sA[3][64 * 32];
  __shared__ __align__(16) bf16 sB[3][4096];

  const int tid = threadIdx.x, wave = tid >> 6, lane = tid & 63;
  const int wr = wave >> 1, wc = wave & 1;
  const int fr = lane & 15, kg = lane >> 4;
  const int lr = lane >> 2, lk = (lane & 3) * 8;

  int ar = rt * 64 + wave * 16 + lr;
  int arc = ar < cnt ? ar : cnt - 1;
  const bf16* aS = hbuf + (size_t)slot[e * T_TOK + arc] * I_DIM + lk;
  const int aOff = wave * 512;

  const int j2 = (lane & 7) >> 1, h2 = lane & 1, nblk2 = lane >> 3;
  const int n2 = nb + nblk2 * 16 + 8 * h2;
  const bf16* bS0 = WB + (size_t)((wave * 2 + 0) * 4 + j2) * H_DIM + n2;
  const bf16* bS1 = WB + (size_t)((wave * 2 + 1) * 4 + j2) * H_DIM + n2;
  const int bOff0 = wave * 1024;
  const int bOff1 = bOff0 + 512;

  f32x4 acc[2][4];
#pragma unroll
  for (int i = 0; i < 2; ++i)
#pragma unroll
    for (int j = 0; j < 4; ++j) acc[i][j] = f32x4{0,0,0,0};

#define STG2(t, bidx) do { size_t ko = (size_t)(t) * 32;    \
    GLOAD16(aS + ko, sA[bidx] + aOff);                      \
    GLOAD16(bS0 + ko * H_DIM, sB[bidx] + bOff0);            \
    GLOAD16(bS1 + ko * H_DIM, sB[bidx] + bOff1); } while (0)

  STG2(0, 0); STG2(1, 1);
  const int NT = I_DIM / 32;  // 16
  int bufc = 0;
  for (int t = 0; t < NT; ++t) {
    int bn = bufc + 2; bn = bn >= 3 ? bn - 3 : bn;
    if (t + 2 < NT) {
      STG2(t + 2, bn);
      asm volatile("s_waitcnt vmcnt(6)" ::: "memory");
    } else if (t + 1 < NT) {
      asm volatile("s_waitcnt vmcnt(3)" ::: "memory");
    } else {
      asm volatile("s_waitcnt vmcnt(0)" ::: "memory");
    }
    __builtin_amdgcn_s_barrier();
    __builtin_amdgcn_sched_barrier(0);
    const bf16* A = sA[bufc];
    bf16x8 a0 = *(const bf16x8*)(A + (wr * 32      + fr) * 32 + kg * 8);
    bf16x8 a1 = *(const bf16x8*)(A + (wr * 32 + 16 + fr) * 32 + kg * 8);
    unsigned bb = lds_addr(sB[bufc]) + (unsigned)((lane >> 4) << 11) + (unsigned)((lane & 15) << 3)
                + (unsigned)(wc * 512);
    bf16x8 b[4];
#pragma unroll
    for (int ni = 0; ni < 4; ++ni)
      b[ni] = cat8(tr_read<0>(bb + ni * 128), tr_read<1024>(bb + ni * 128));
    asm volatile("s_waitcnt lgkmcnt(0)" ::: "memory");
    __builtin_amdgcn_sched_barrier(0);
    __builtin_amdgcn_s_setprio(1);
#pragma unroll
    for (int ni = 0; ni < 4; ++ni) {
      acc[0][ni] = __builtin_amdgcn_mfma_f32_16x16x32_bf16(a0, b[ni], acc[0][ni], 0, 0, 0);
      acc[1][ni] = __builtin_amdgcn_mfma_f32_16x16x32_bf16(a1, b[ni], acc[1][ni], 0, 0, 0);
    }
    __builtin_amdgcn_s_setprio(0);
    __builtin_amdgcn_sched_barrier(0);
    __builtin_amdgcn_s_barrier();
    bufc = bufc == 2 ? 0 : bufc + 1;
  }
#undef STG2

#pragma unroll
  for (int mi = 0; mi < 2; ++mi) {
#pragma unroll
    for (int j = 0; j < 4; ++j) {
      int grow = rt * 64 + wr * 32 + mi * 16 + kg * 4 + j;
      if (grow < cnt) {
        bf16* orow = obuf + (size_t)slot[e * T_TOK + grow] * H_DIM + nb + wc * 64 + fr;
#pragma unroll
        for (int ni = 0; ni < 4; ++ni)
          orow[ni * 16] = (bf16)acc[mi][ni][j];
      }
    }
  }
}

// ---------------- reduce: out[t] = sum_k obuf[t*4+k] + obuf[4096+t] (bf16 -> fp32) ----------------
__global__ void reduce_kernel(const bf16* __restrict__ obuf, float* __restrict__ out) {
  const int t = blockIdx.x;
  const int c = threadIdx.x;   // 256 chunks of 4 elems per row
  const bf16x4* o4 = (const bf16x4*)obuf;
  float4 s; s.x = s.y = s.z = s.w = 0.f;
  int rows[5] = {t * 4, t * 4 + 1, t * 4 + 2, t * 4 + 3, T_TOK * TOPK + t};
#pragma unroll
  for (int r = 0; r < 5; ++r) {
    bf16x4 v = o4[(size_t)rows[r] * 256 + c];
    s.x += (float)v[0]; s.y += (float)v[1]; s.z += (float)v[2]; s.w += (float)v[3];
  }
  ((float4*)out)[(size_t)t * 256 + c] = s;
}

extern "C" void kernel_launch(void* const* d_in, const int* in_sizes, int n_in,
                              void* d_out, int out_size, void* d_ws, size_t ws_size,
                              hipStream_t stream) {
  const float* x   = (const float*)d_in[0];
  const float* gw  = (const float*)d_in[1];
  const float* wgu = (const float*)d_in[2];
  const float* wd  = (const float*)d_in[3];
  const float* sgu = (const float*)d_in[4];
  const float* sd  = (const float*)d_in[5];
  float* out = (float*)d_out;

  char* ws = (char*)d_ws;
  int*   counts = (int*)  (ws);                 // 1 KB
  int*   tok    = (int*)  (ws + 1024);          // 68 KB
  float* wtA    = (float*)(ws + 70656);         // 68 KB
  int*   slotA  = (int*)  (ws + 140288);        // 68 KB
  int*   topk_e = (int*)  (ws + 209920);        // 16 KB
  float* topk_w = (float*)(ws + 226304);        // 16 KB
  bf16*  xb     = (bf16*) (ws + 245760);        // 2 MB
  bf16*  hbuf   = (bf16*) (ws + 2342912);       // 5.25 MB
  bf16*  wguB   = (bf16*) (ws + 7585792);       // 32 MB  natural [E][1024][1024]
  bf16*  wdB    = (bf16*) (ws + 41140224);      // 16 MB  natural [E][512][1024]
  bf16*  sguB   = (bf16*) (ws + 57917440);      // 2 MB
  bf16*  sdB    = (bf16*) (ws + 60014592);      // 1 MB
  // obuf (10 MB bf16 [5120][1024]) aliases wguB: dead after gemm1, rewritten by
  // prep before gemm1 on every call.
  bf16*  obuf   = (bf16*) (ws + 7585792);

  prep_kernel<<<1412, 256, 0, stream>>>(x, xb, wgu, wguB, sgu, sguB,
                                        gw, topk_e, topk_w, counts, tok, wtA, slotA);
  router_build_kernel<<<E_NUM, 256, 0, stream>>>(topk_e, topk_w, counts, tok, wtA, slotA);
  gemm1_kernel<<<dim3(8, 16, 26), 256, 0, stream>>>(xb, wguB, sguB, counts, tok, wtA, slotA,
                                                    hbuf, wd, wdB, sd, sdB);
  gemm2_kernel<<<dim3(8, 16, 17), 256, 0, stream>>>(hbuf, wdB, sdB, counts, slotA, obuf);
  reduce_kernel<<<T_TOK, 256, 0, stream>>>(obuf, out);
}